// Round 10
// baseline (242.627 us; speedup 1.0000x reference)
//
#include <hip/hip_runtime.h>
#include <stdint.h>

#define B_ 16
#define S_ 128
#define H_ 768
#define K_ 4
#define L_ 2
#define T_ (B_*S_)   // 2048

typedef __attribute__((ext_vector_type(4))) float f32x4;
typedef __attribute__((ext_vector_type(16))) float f32x16;
typedef __attribute__((ext_vector_type(8))) short s16x8;
typedef __bf16 bf16x8 __attribute__((ext_vector_type(8)));
typedef unsigned short u16;

// ---------- bf16 helpers ----------
__device__ inline u16 f2bf(float f) {
    union { float f; uint32_t u; } v; v.f = f;
    uint32_t u = v.u;
    return (u16)((u + 0x7fffu + ((u >> 16) & 1u)) >> 16);
}

__device__ inline ushort4 f2bf4(float4 v) {
    ushort4 r; r.x = f2bf(v.x); r.y = f2bf(v.y); r.z = f2bf(v.z); r.w = f2bf(v.w);
    return r;
}

// ---------- MFMA wrappers: tolerant to either builtin signature ----------
template <typename T>
__device__ inline auto mfma16_impl(T a, T b, f32x4 c, int)
    -> decltype(__builtin_amdgcn_mfma_f32_16x16x32_bf16(a, b, c, 0, 0, 0)) {
    return __builtin_amdgcn_mfma_f32_16x16x32_bf16(a, b, c, 0, 0, 0);
}
template <typename T>
__device__ inline f32x4 mfma16_impl(T a, T b, f32x4 c, long) {
    return __builtin_amdgcn_mfma_f32_16x16x32_bf16(
        __builtin_bit_cast(bf16x8, a), __builtin_bit_cast(bf16x8, b), c, 0, 0, 0);
}
__device__ inline f32x4 mfma16(s16x8 a, s16x8 b, f32x4 c) {
    return mfma16_impl(a, b, c, 0);
}

template <typename T>
__device__ inline auto mfma32_impl(T a, T b, f32x16 c, int)
    -> decltype(__builtin_amdgcn_mfma_f32_32x32x16_bf16(a, b, c, 0, 0, 0)) {
    return __builtin_amdgcn_mfma_f32_32x32x16_bf16(a, b, c, 0, 0, 0);
}
template <typename T>
__device__ inline f32x16 mfma32_impl(T a, T b, f32x16 c, long) {
    return __builtin_amdgcn_mfma_f32_32x32x16_bf16(
        __builtin_bit_cast(bf16x8, a), __builtin_bit_cast(bf16x8, b), c, 0, 0, 0);
}
__device__ inline f32x16 mfma32(s16x8 a, s16x8 b, f32x16 c) {
    return mfma32_impl(a, b, c, 0);
}

// ---------- async global->LDS, 16B/lane ----------
__device__ inline void gload_lds16(const void* g, void* l) {
    __builtin_amdgcn_global_load_lds(
        (__attribute__((address_space(1))) void*)(g),
        (__attribute__((address_space(3))) void*)(l), 16, 0, 0);
}

// ---- gemm2 helpers (unchanged, proven) ----
__device__ inline void stage_tile(const char* gbase, int rowStrideBytes, u16* lds, int tid) {
    const int lane = tid & 63;
    const int w = tid >> 6;
    const int lr = lane >> 3;
    const int cb = (lane & 7) << 4;
    #pragma unroll
    for (int j = 0; j < 4; ++j) {
        const int seg = j * 4 + w;
        const int row = seg * 8 + lr;
        const int sb = cb ^ ((row & 7) << 4);
        gload_lds16(gbase + (size_t)row * rowStrideBytes + sb, lds + seg * 512);
    }
}

__device__ inline void stage64(const char* gbase, int rowStrideBytes, char* lds, int tid) {
    const int lane = tid & 63;
    const int w = tid >> 6;
    const int lr = lane >> 3;
    const int cb = (lane & 7) << 4;
    #pragma unroll
    for (int j = 0; j < 2; ++j) {
        const int seg = j * 4 + w;
        const int row = seg * 8 + lr;
        const int sb = cb ^ ((row & 7) << 4);
        gload_lds16(gbase + (size_t)row * rowStrideBytes + sb, lds + seg * 1024);
    }
}

__device__ inline s16x8 read_frag(const u16* lds, int row, int colByte) {
    const int bir = colByte ^ ((row & 7) << 4);
    return *(const s16x8*)((const char*)lds + row * 128 + bir);
}

// ---------- prep kernels ----------
__global__ void prep_x(const float* __restrict__ sent, u16* __restrict__ X0) {
    const int i4 = blockIdx.x * blockDim.x + threadIdx.x;
    if (i4 < T_ * H_ / 4) ((ushort4*)X0)[i4] = f2bf4(((const float4*)sent)[i4]);
}

// adjA[p][b][t][s]: p=dir*4+k; dir 0 (in): adj[b,k,s,t] (transposed), dir 1 (out): adj[b,k,t,s]
__global__ void prep_adj(const float* __restrict__ adj, u16* __restrict__ adjA) {
    const int idx = blockIdx.x * blockDim.x + threadIdx.x;
    const int s = idx & 127;
    const int t = (idx >> 7) & 127;
    const int b = (idx >> 14) & 15;
    const int p = idx >> 18;
    const int dir = p >> 2, k = p & 3;
    const float v = dir ? adj[(((size_t)b * K_ + k) * S_ + t) * S_ + s]
                        : adj[(((size_t)b * K_ + k) * S_ + s) * S_ + t];
    adjA[idx] = f2bf(v);
}

// ---------- weight pack: 32x32x16-fragment order ----------
// Wpk[l][mat 17][nT 24][kT 48][lane 64][8 bf16]; chunk (nT,kT) lane l:
// W[nT*32 + (l&31)][kT*16 + (l>>5)*8 + 0..7]. mat = p*2+role for p<8; 16 = loop.
__global__ void pack_weights32(const float* __restrict__ W_in,  const float* __restrict__ W_out,
                               const float* __restrict__ Wg_in, const float* __restrict__ Wg_out,
                               const float* __restrict__ W_loop, u16* __restrict__ Wpk) {
    __shared__ u16 slab[32][776];
    const int tid = threadIdx.x;
    const int bid = blockIdx.x;              // l*17*24 + mat*24 + nT
    const int nT  = bid % 24;
    const int mat = (bid / 24) % 17;
    const int l   = bid / (24 * 17);

    const float* src;
    if (mat < 16) {
        const int p = mat >> 1, slot = mat & 1;
        const int dir = p >> 2, k = p & 3;
        const float* t = slot ? (dir ? Wg_out : Wg_in) : (dir ? W_out : W_in);
        src = t + ((size_t)l * K_ + k) * (H_ * H_);
    } else {
        src = W_loop + (size_t)l * (H_ * H_);
    }
    #pragma unroll
    for (int it = 0; it < 24; ++it) {
        const int idx = it * 256 + tid;      // 6144 float4 = 32 rows x 192
        const int row = idx / 192, c4 = idx % 192;
        float4 v = ((const float4*)(src + (size_t)(nT * 32 + row) * H_))[c4];
        slab[row][c4 * 4 + 0] = f2bf(v.x);
        slab[row][c4 * 4 + 1] = f2bf(v.y);
        slab[row][c4 * 4 + 2] = f2bf(v.z);
        slab[row][c4 * 4 + 3] = f2bf(v.w);
    }
    __syncthreads();
    const int q = tid >> 6, lane = tid & 63;
    const int row = lane & 31, kg = lane >> 5;
    u16* outBase = Wpk + (((size_t)(l * 17 + mat) * 24 + nT) * 48) * 512;
    #pragma unroll
    for (int it = 0; it < 12; ++it) {
        const int kT = it * 4 + q;
        s16x8 v = *(const s16x8*)&slab[row][kT * 16 + kg * 8];
        *(s16x8*)(outBase + (size_t)kT * 512 + lane * 8) = v;
    }
}

// ---------- GEMM 1: 32x32x16 MFMA, role-split waves, DISTANCE-2 A-prefetch ----------
// Quad-buffered A (4x8KB). body(t): stage A(t+2), load B(t+1); ONE vmcnt(6) before
// MFMA (drains A(t+1)+B(t), both issued a full K-tile ago); raw s_barrier after
// (no forced vmcnt(0) drain). Tail peeled with vmcnt(4)/vmcnt(0).
// grid 1632 = 1536 gated (p,y,m) + 96 loop; XCD swizzle (1632 = 8*204).
__global__ __launch_bounds__(256, 4)
void gemm1_kernel(const u16* __restrict__ Xb, const u16* __restrict__ Wpk,
                  const float* __restrict__ bg_in, const float* __restrict__ bg_out,
                  const float* __restrict__ b_in,  const float* __restrict__ b_out,
                  int layer,
                  u16* __restrict__ Rel2, float* __restrict__ SBuf) {
    __shared__ __align__(16) char smem[32768];   // loop: 4x8KB A; epilogue: 32KB sig

    const int tid = threadIdx.x;
    const int lane = tid & 63;
    const int w = tid >> 6;
    const int wm = w >> 1;          // 0..1 token half (64 rows)
    const int role = w & 1;         // 0 = rel, 1 = gate
    const int l31 = lane & 31;
    const int kg = lane >> 5;       // 0..1 k-group

    const int id = blockIdx.x;
    const int task = (id & 7) * 204 + (id >> 3);   // bijective, 1632 = 8*204
    int p, y, m;
    if (task < 1536) { p = task / 192; const int r = task % 192; y = r / 16; m = r % 16; }
    else             { const int q2 = task - 1536; p = 8; y = q2 / 16; m = q2 % 16; }
    const int m0 = m * 128;

    int mat, nT0;
    if (p < 8) { mat = p * 2 + role; nT0 = y * 2; }
    else       { mat = 16;           nT0 = y * 4 + role * 2; }
    const u16* pB = Wpk + (((size_t)(layer * 17 + mat) * 24 + nT0) * 48) * 512 + lane * 8;
    const char* gA = (const char*)Xb + (size_t)m0 * (H_ * 2);

    auto STAGE_A = [&](int t, int c) {
        char* base = smem + c * 8192;
        #pragma unroll
        for (int j = 0; j < 2; ++j) {
            const int srow = j * 64 + w * 16 + (lane >> 2);
            const int sc = (lane & 3) ^ ((srow >> 1) & 3);
            gload_lds16(gA + (size_t)srow * (H_ * 2) + t * 64 + sc * 16,
                        base + (j * 256 + w * 64) * 16);
        }
    };
    auto LOADB = [&](s16x8* dst, int t) {
        #pragma unroll
        for (int j = 0; j < 2; ++j)
            #pragma unroll
            for (int kq = 0; kq < 2; ++kq)
                dst[j * 2 + kq] = *(const s16x8*)(pB + ((size_t)j * 48 + 2 * t + kq) * 512);
    };

    f32x16 acc[2][2];
    #pragma unroll
    for (int q = 0; q < 2; ++q)
        #pragma unroll
        for (int j = 0; j < 2; ++j) acc[q][j] = (f32x16)(0.0f);

    s16x8 bA[4], bB[4];

    // prologue: A(0), A(1) staged; B(0) loaded; full drain once.
    STAGE_A(0, 0);
    STAGE_A(1, 1);
    LOADB(bA, 0);
    asm volatile("s_waitcnt vmcnt(0)" ::: "memory");
    __builtin_amdgcn_s_barrier();
    __builtin_amdgcn_sched_barrier(0);

#define K_BODY(T, CUR, NXT, WAITSTR, STG, LDB)                                 \
    {                                                                          \
        if (STG) STAGE_A((T) + 2, ((T) + 2) & 3);                              \
        if (LDB) LOADB(NXT, (T) + 1);                                          \
        __builtin_amdgcn_sched_barrier(0);                                     \
        const u16* lA = (const u16*)(smem + ((T) & 3) * 8192);                 \
        s16x8 a[2][2];                                                         \
        _Pragma("unroll") for (int q = 0; q < 2; ++q) {                        \
            _Pragma("unroll") for (int kq = 0; kq < 2; ++kq) {                 \
                const int row = wm * 64 + q * 32 + l31;                        \
                const int o16 = (kq * 2 + kg) ^ ((row >> 1) & 3);              \
                a[q][kq] = *(const s16x8*)((const char*)lA + row * 64 + o16 * 16); \
            }                                                                  \
        }                                                                      \
        asm volatile(WAITSTR ::: "memory");                                    \
        __builtin_amdgcn_sched_barrier(0);                                     \
        __builtin_amdgcn_s_setprio(1);                                         \
        _Pragma("unroll") for (int q = 0; q < 2; ++q) {                        \
            _Pragma("unroll") for (int j = 0; j < 2; ++j) {                    \
                _Pragma("unroll") for (int kq = 0; kq < 2; ++kq) {             \
                    acc[q][j] = mfma32(a[q][kq], (CUR)[j * 2 + kq], acc[q][j]); \
                }                                                              \
            }                                                                  \
        }                                                                      \
        __builtin_amdgcn_s_setprio(0);                                         \
        __builtin_amdgcn_s_barrier();                                          \
        __builtin_amdgcn_sched_barrier(0);                                     \
    }

    for (int t = 0; t < 22; t += 2) {
        K_BODY(t,     bA, bB, "s_waitcnt vmcnt(6)", true, true)
        K_BODY(t + 1, bB, bA, "s_waitcnt vmcnt(6)", true, true)
    }
    // tail: t=22 (stage done; load B(23)), t=23 (drain all)
    K_BODY(22, bA, bB, "s_waitcnt vmcnt(4)", false, true)
    K_BODY(23, bB, bA, "s_waitcnt vmcnt(0)", false, false)
#undef K_BODY

    // ---------------- epilogue (V0 scatter — A/B-exonerated in r9) ----------------
    // C/D 32x32 layout: col = l31, row = (r&3) + 8*(r>>2) + 4*kg; r = g*4+rr
    if (p < 8) {
        const int dir = p >> 2, kk = p & 3;
        float* sig = (float*)smem;   // [col 64][tok 128] f32, byte ^= (col&7)<<4
        if (role == 1) {
            const float* bgp = (dir ? bg_out : bg_in) + ((size_t)layer * K_ + kk) * H_;
            #pragma unroll
            for (int q = 0; q < 2; ++q) {
                #pragma unroll
                for (int j = 0; j < 2; ++j) {
                    const int col = j * 32 + l31;
                    const float bgv = bgp[y * 64 + col];
                    #pragma unroll
                    for (int g = 0; g < 4; ++g) {
                        const int tok0 = wm * 64 + q * 32 + g * 8 + kg * 4;
                        f32x4 sv;
                        #pragma unroll
                        for (int rr = 0; rr < 4; ++rr) {
                            const float gv = acc[q][j][g * 4 + rr] + bgv;
                            sv[rr] = 1.f / (1.f + __expf(-gv));
                        }
                        *(f32x4*)((char*)sig + ((col * 512 + tok0 * 4) ^ ((col & 7) << 4))) = sv;
                    }
                }
            }
        }
        __syncthreads();
        if (role == 0) {
            const float* brp = (dir ? b_out : b_in) + ((size_t)layer * K_ + kk) * H_;
            const float* sigr = (const float*)smem;
            #pragma unroll
            for (int q = 0; q < 2; ++q) {
                #pragma unroll
                for (int j = 0; j < 2; ++j) {
                    const int col = j * 32 + l31;
                    const int h = y * 64 + col;
                    const float brv = brp[h];
                    u16* dst = Rel2 + (((size_t)p * B_ + m) * H_ + h) * S_;
                    #pragma unroll
                    for (int g = 0; g < 4; ++g) {
                        const int tok0 = wm * 64 + q * 32 + g * 8 + kg * 4;
                        f32x4 sv = *(const f32x4*)((const char*)sigr +
                                   ((col * 512 + tok0 * 4) ^ ((col & 7) << 4)));
                        ushort4 pk;
                        pk.x = f2bf(0.5f * (acc[q][j][g * 4 + 0] + brv) * sv[0]);
                        pk.y = f2bf(0.5f * (acc[q][j][g * 4 + 1] + brv) * sv[1]);
                        pk.z = f2bf(0.5f * (acc[q][j][g * 4 + 2] + brv) * sv[2]);
                        pk.w = f2bf(0.5f * (acc[q][j][g * 4 + 3] + brv) * sv[3]);
                        *(ushort4*)(dst + tok0) = pk;
                    }
                }
            }
        }
    } else {
        #pragma unroll
        for (int q = 0; q < 2; ++q) {
            #pragma unroll
            for (int j = 0; j < 2; ++j) {
                const int h = y * 128 + role * 64 + j * 32 + l31;
                #pragma unroll
                for (int g = 0; g < 4; ++g) {
                    const int tok0 = m0 + wm * 64 + q * 32 + g * 8 + kg * 4;
                    #pragma unroll
                    for (int rr = 0; rr < 4; ++rr)
                        SBuf[(size_t)(tok0 + rr) * H_ + h] = acc[q][j][g * 4 + rr];
                }
            }
        }
    }
}

// ---------- GEMM 2: adjacency contraction + loop term + ReLU (unchanged) ----------
__global__ __launch_bounds__(256, 2)
void gemm2_kernel(const u16* __restrict__ adjA, const u16* __restrict__ Rel2,
                  const float* __restrict__ SBuf,
                  u16* __restrict__ Xn, float* __restrict__ Out, int lastLayer) {
    __shared__ __align__(16) char smem2[49152];   // 2 x (A 16K + B 8K)

    const int tid = threadIdx.x;
    const int lane = tid & 63;
    const int w = tid >> 6;
    const int wm = w >> 1, wn = w & 1;
    const int l15 = lane & 15;
    const int hi16 = (lane >> 4) << 4;
    const int h0 = blockIdx.x * 64;
    const int b = blockIdx.y;

    auto STAGE = [&](int q, int c) {
        const int p = q >> 1, sc = q & 1;
        const char* Ab = (const char*)adjA + ((size_t)p * B_ + b) * (S_ * S_ * 2) + sc * 128;
        const char* Bb = (const char*)Rel2 + (((size_t)p * B_ + b) * H_ + h0) * (S_ * 2) + sc * 128;
        char* base = smem2 + c * 24576;
        stage_tile(Ab, S_ * 2, (u16*)base, tid);
        stage64(Bb, S_ * 2, base + 16384, tid);
    };

    const f32x4 zf = {0.f, 0.f, 0.f, 0.f};
    f32x4 acc[4][2];
    #pragma unroll
    for (int i = 0; i < 4; ++i)
        #pragma unroll
        for (int j = 0; j < 2; ++j) acc[i][j] = zf;

    STAGE(0, 0);
    __syncthreads();

    for (int q = 0; q < 16; ++q) {
        const int c = q & 1;
        if (q < 15) STAGE(q + 1, c ^ 1);
        const u16* lA = (const u16*)(smem2 + c * 24576);
        const u16* lB = (const u16*)(smem2 + c * 24576 + 16384);
        #pragma unroll
        for (int kq = 0; kq < 2; ++kq) {
            const int ck = kq * 64 + hi16;
            s16x8 a[4], bb[2];
            #pragma unroll
            for (int i = 0; i < 4; ++i)
                a[i] = read_frag(lA, wm * 64 + i * 16 + l15, ck);
            #pragma unroll
            for (int j = 0; j < 2; ++j)
                bb[j] = read_frag(lB, wn * 32 + j * 16 + l15, ck);
            #pragma unroll
            for (int i = 0; i < 4; ++i)
                #pragma unroll
                for (int j = 0; j < 2; ++j)
                    acc[i][j] = mfma16(a[i], bb[j], acc[i][j]);
        }
        __syncthreads();
    }

    #pragma unroll
    for (int i = 0; i < 4; ++i) {
        const int tl = wm * 64 + i * 16 + ((lane >> 4) << 2);
        #pragma unroll
        for (int j = 0; j < 2; ++j) {
            const int h = h0 + wn * 32 + j * 16 + l15;
            #pragma unroll
            for (int r = 0; r < 4; ++r) {
                const size_t t = (size_t)b * S_ + tl + r;
                float v = acc[i][j][r] + SBuf[t * H_ + h];
                v = fmaxf(v, 0.f);
                if (lastLayer) Out[t * H_ + h] = v;
                else           Xn[t * H_ + h] = f2bf(v);
            }
        }
    }
}

// ---------- launch ----------
extern "C" void kernel_launch(void* const* d_in, const int* in_sizes, int n_in,
                              void* d_out, int out_size, void* d_ws, size_t ws_size,
                              hipStream_t stream) {
    const float* sent   = (const float*)d_in[0];
    const float* adj    = (const float*)d_in[1];
    const float* W_in   = (const float*)d_in[2];
    const float* b_in   = (const float*)d_in[3];
    const float* W_out  = (const float*)d_in[4];
    const float* b_out  = (const float*)d_in[5];
    const float* Wg_in  = (const float*)d_in[6];
    const float* bg_in  = (const float*)d_in[7];
    const float* Wg_out = (const float*)d_in[8];
    const float* bg_out = (const float*)d_in[9];
    const float* W_loop = (const float*)d_in[10];

    char* ws = (char*)d_ws;
    u16* Wpk    = (u16*)(ws);                  // L*17*24*48*1024 B = 40,108,032 B
    u16* adjA   = (u16*)(ws + 40108032);       //  4,194,304 B
    u16* X0     = (u16*)(ws + 44302336);       //  3,145,728 B
    u16* X1     = (u16*)(ws + 47448064);       //  3,145,728 B
    u16* Rel2   = (u16*)(ws + 50593792);       // 25,165,824 B
    float* SBuf = (float*)(ws + 75759616);     //  6,291,456 B  (end 82,051,072)

    prep_x<<<1536, 256, 0, stream>>>(sent, X0);
    prep_adj<<<8192, 256, 0, stream>>>(adj, adjA);
    pack_weights32<<<L_ * 17 * 24, 256, 0, stream>>>(W_in, W_out, Wg_in, Wg_out, W_loop, Wpk);

    u16* Xc = X0;
    u16* Xn = X1;
    for (int l = 0; l < L_; ++l) {
        gemm1_kernel<<<1632, 256, 0, stream>>>(Xc, Wpk, bg_in, bg_out, b_in, b_out,
                                               l, Rel2, SBuf);
        gemm2_kernel<<<dim3(12, 16), 256, 0, stream>>>(adjA, Rel2, SBuf, Xn,
                                                       (float*)d_out, l == L_ - 1);
        u16* t = Xc; Xc = Xn; Xn = t;
    }
}

// Round 11
// 161.665 us; speedup vs baseline: 1.5008x; 1.5008x over previous
//
#include <hip/hip_runtime.h>
#include <stdint.h>

#define B_ 16
#define S_ 128
#define H_ 768
#define K_ 4
#define L_ 2
#define T_ (B_*S_)   // 2048

typedef __attribute__((ext_vector_type(4))) float f32x4;
typedef __attribute__((ext_vector_type(8))) short s16x8;
typedef __bf16 bf16x8 __attribute__((ext_vector_type(8)));
typedef unsigned short u16;

// ---------- bf16 helpers ----------
__device__ inline u16 f2bf(float f) {
    union { float f; uint32_t u; } v; v.f = f;
    uint32_t u = v.u;
    return (u16)((u + 0x7fffu + ((u >> 16) & 1u)) >> 16);
}

__device__ inline ushort4 f2bf4(float4 v) {
    ushort4 r; r.x = f2bf(v.x); r.y = f2bf(v.y); r.z = f2bf(v.z); r.w = f2bf(v.w);
    return r;
}

// ---------- MFMA wrapper: tolerant to either builtin signature ----------
template <typename T>
__device__ inline auto mfma16_impl(T a, T b, f32x4 c, int)
    -> decltype(__builtin_amdgcn_mfma_f32_16x16x32_bf16(a, b, c, 0, 0, 0)) {
    return __builtin_amdgcn_mfma_f32_16x16x32_bf16(a, b, c, 0, 0, 0);
}
template <typename T>
__device__ inline f32x4 mfma16_impl(T a, T b, f32x4 c, long) {
    return __builtin_amdgcn_mfma_f32_16x16x32_bf16(
        __builtin_bit_cast(bf16x8, a), __builtin_bit_cast(bf16x8, b), c, 0, 0, 0);
}
__device__ inline f32x4 mfma16(s16x8 a, s16x8 b, f32x4 c) {
    return mfma16_impl(a, b, c, 0);
}

// ---------- async global->LDS, 16B/lane ----------
__device__ inline void gload_lds16(const void* g, void* l) {
    __builtin_amdgcn_global_load_lds(
        (__attribute__((address_space(1))) void*)(g),
        (__attribute__((address_space(3))) void*)(l), 16, 0, 0);
}

// ---- 512-thread (8-wave) stage of a 128x64-bf16 tile (XOR-swizzled, proven r3) ----
__device__ inline void stage128(const char* gRow0, int rowStrideBytes, char* ldsBase, int tid) {
    const int lane = tid & 63;
    const int w = tid >> 6;           // 0..7
    const int lr = lane >> 3;
    #pragma unroll
    for (int j = 0; j < 2; ++j) {
        const int seg = w * 2 + j;          // 0..15
        const int row = seg * 8 + lr;       // 0..127
        const int sb = ((lane & 7) << 4) ^ ((row & 7) << 4);
        gload_lds16(gRow0 + (size_t)row * rowStrideBytes + sb,
                    ldsBase + seg * 1024);
    }
}

// ---- 256-thread (4-wave) stage of a 128x64-bf16 tile (gemm2) ----
__device__ inline void stage_tile(const char* gbase, int rowStrideBytes, u16* lds, int tid) {
    const int lane = tid & 63;
    const int w = tid >> 6;
    const int lr = lane >> 3;
    const int cb = (lane & 7) << 4;
    #pragma unroll
    for (int j = 0; j < 4; ++j) {
        const int seg = j * 4 + w;
        const int row = seg * 8 + lr;
        const int sb = cb ^ ((row & 7) << 4);
        gload_lds16(gbase + (size_t)row * rowStrideBytes + sb, lds + seg * 512);
    }
}

// ---- 256-thread stage of a 64x64-bf16 tile (gemm2) ----
__device__ inline void stage64(const char* gbase, int rowStrideBytes, char* lds, int tid) {
    const int lane = tid & 63;
    const int w = tid >> 6;
    const int lr = lane >> 3;
    const int cb = (lane & 7) << 4;
    #pragma unroll
    for (int j = 0; j < 2; ++j) {
        const int seg = j * 4 + w;
        const int row = seg * 8 + lr;
        const int sb = cb ^ ((row & 7) << 4);
        gload_lds16(gbase + (size_t)row * rowStrideBytes + sb, lds + seg * 1024);
    }
}

// Swizzled ds_read_b128 of an MFMA fragment (128-B rows, any contiguous row count)
__device__ inline s16x8 read_frag(const u16* lds, int row, int colByte) {
    const int bir = colByte ^ ((row & 7) << 4);
    return *(const s16x8*)((const char*)lds + row * 128 + bir);
}

// ---------- prep kernels (r1's proven versions) ----------
__global__ void prep_weights(const float* __restrict__ Wg_in, const float* __restrict__ Wg_out,
                             const float* __restrict__ W_in,  const float* __restrict__ W_out,
                             const float* __restrict__ W_loop, const float* __restrict__ sent,
                             u16* __restrict__ Wg_all, u16* __restrict__ W_all,
                             u16* __restrict__ Wl, u16* __restrict__ X0) {
    const int i4 = blockIdx.x * blockDim.x + threadIdx.x;   // float4 index
    const int NW4 = L_ * K_ * H_ * H_ / 4;                  // 1,179,648
    const int KHH4 = K_ * H_ * H_ / 4;
    if (i4 < NW4) {
        const int l = i4 / KHH4;
        const int rem = i4 - l * KHH4;
        const int d0 = (l * 2) * KHH4 + rem;
        const int d1 = d0 + KHH4;
        ((ushort4*)Wg_all)[d0] = f2bf4(((const float4*)Wg_in)[i4]);
        ((ushort4*)Wg_all)[d1] = f2bf4(((const float4*)Wg_out)[i4]);
        ((ushort4*)W_all)[d0]  = f2bf4(((const float4*)W_in)[i4]);
        ((ushort4*)W_all)[d1]  = f2bf4(((const float4*)W_out)[i4]);
    }
    if (i4 < L_ * H_ * H_ / 4)  ((ushort4*)Wl)[i4] = f2bf4(((const float4*)W_loop)[i4]);
    if (i4 < T_ * H_ / 4)       ((ushort4*)X0)[i4] = f2bf4(((const float4*)sent)[i4]);
}

// adjA[p][b][t][s]: p=dir*4+k; dir 0 (in): adj[b,k,s,t] (transposed), dir 1 (out): adj[b,k,t,s]
__global__ void prep_adj(const float* __restrict__ adj, u16* __restrict__ adjA) {
    const int idx = blockIdx.x * blockDim.x + threadIdx.x;
    const int s = idx & 127;
    const int t = (idx >> 7) & 127;
    const int b = (idx >> 14) & 15;
    const int p = idx >> 18;
    const int dir = p >> 2, k = p & 3;
    const float v = dir ? adj[(((size_t)b * K_ + k) * S_ + t) * S_ + s]
                        : adj[(((size_t)b * K_ + k) * S_ + s) * S_ + t];
    adjA[idx] = f2bf(v);
}

// ---------- GEMM 1: 256tok x 128h (rel+gate), one p-problem per XCD ----------
// r3's proven 2-phase schedule, bigger tile. 512 threads = 8 waves (2m x 4n),
// per-wave 128tok x 32h rel+gate (acc 128 VGPR). BK=64, LDS 2 x 64KB dbuf.
// grid 384 = 8p x 6y x 8m; task=(bid&7)*48+(bid>>3) puts p == XCD (weights
// 2.36MB -> L2-resident per XCD). Self-loop handled by gemm2.
__global__ __launch_bounds__(512, 2)
void gemm1_kernel(const u16* __restrict__ Xb,
                  const u16* __restrict__ Wg_all, const u16* __restrict__ W_all,
                  const float* __restrict__ bg_in, const float* __restrict__ bg_out,
                  const float* __restrict__ b_in,  const float* __restrict__ b_out,
                  int layer, u16* __restrict__ Rel2) {
    __shared__ __align__(16) char smem[131072];

    const int tid = threadIdx.x;
    const int lane = tid & 63;
    const int w = tid >> 6;
    const int wm = w >> 2;                 // 0..1 (128-tok half)
    const int wn = w & 3;                  // 0..3 (32-h slice)
    const int l15 = lane & 15;
    const int hi16 = (lane >> 4) << 4;

    const int bid = blockIdx.x;
    const int task = (bid & 7) * 48 + (bid >> 3);   // bijective, 384 = 8*48
    const int p = task / 48;               // == bid & 7  -> one p per XCD
    const int r = task % 48;
    const int y = r >> 3;                  // 0..5
    const int m = r & 7;                   // 0..7
    const int m0 = m * 256;
    const int n0 = y * 128;
    const int dir = p >> 2, kk = p & 3;

    const size_t woff = ((size_t)(layer * 2 + dir) * K_ + kk) * (size_t)(H_ * H_);
    const char* gA  = (const char*)Xb + (size_t)m0 * (H_ * 2);
    const char* gBr = (const char*)(W_all + woff)  + (size_t)n0 * (H_ * 2);
    const char* gBg = (const char*)(Wg_all + woff) + (size_t)n0 * (H_ * 2);

    auto STAGE = [&](int kt, int c) {
        char* base = smem + c * 65536;
        stage128(gA + (size_t)kt * 128, H_ * 2, base, tid);
        stage128(gA + (size_t)128 * (H_ * 2) + (size_t)kt * 128, H_ * 2, base + 16384, tid);
        stage128(gBr + (size_t)kt * 128, H_ * 2, base + 32768, tid);
        stage128(gBg + (size_t)kt * 128, H_ * 2, base + 49152, tid);
    };

    const f32x4 zf = {0.f, 0.f, 0.f, 0.f};
    f32x4 accr[8][2], accg[8][2];
    #pragma unroll
    for (int i = 0; i < 8; ++i)
        #pragma unroll
        for (int j = 0; j < 2; ++j) { accr[i][j] = zf; accg[i][j] = zf; }

    STAGE(0, 0);
    __syncthreads();

    for (int t = 0; t < 12; ++t) {
        const int c = t & 1;
        if (t < 11) STAGE(t + 1, c ^ 1);          // prefetch next tile first
        const u16* lA  = (const u16*)(smem + c * 65536);        // 256 rows (tok)
        const u16* lBr = (const u16*)(smem + c * 65536 + 32768); // 128 rows (h)
        const u16* lBg = (const u16*)(smem + c * 65536 + 49152);
        #pragma unroll
        for (int kq = 0; kq < 2; ++kq) {
            const int ck = kq * 64 + hi16;
            s16x8 a[8], br[2], bg[2];
            #pragma unroll
            for (int i = 0; i < 8; ++i)
                a[i] = read_frag(lA, wm * 128 + i * 16 + l15, ck);
            #pragma unroll
            for (int j = 0; j < 2; ++j) {
                br[j] = read_frag(lBr, wn * 32 + j * 16 + l15, ck);
                bg[j] = read_frag(lBg, wn * 32 + j * 16 + l15, ck);
            }
            #pragma unroll
            for (int i = 0; i < 8; ++i) {
                #pragma unroll
                for (int j = 0; j < 2; ++j) {
                    accr[i][j] = mfma16(a[i], br[j], accr[i][j]);
                    accg[i][j] = mfma16(a[i], bg[j], accg[i][j]);
                }
            }
        }
        __syncthreads();
    }

    // ---------------- epilogue (wave-local, r3 pattern) ----------------
    const float* bgp = (dir ? bg_out : bg_in) + ((size_t)layer * K_ + kk) * H_;
    const float* brp = (dir ? b_out  : b_in ) + ((size_t)layer * K_ + kk) * H_;
    #pragma unroll
    for (int j = 0; j < 2; ++j) {
        const int h = n0 + wn * 32 + j * 16 + l15;
        const float bgv = bgp[h];
        const float brv = brp[h];
        #pragma unroll
        for (int i = 0; i < 8; ++i) {
            const int tl = wm * 128 + i * 16 + ((lane >> 4) << 2);   // 0..255
            const int bidx = m * 2 + (tl >> 7);
            const int s0 = tl & 127;
            u16 tmp[4];
            #pragma unroll
            for (int rr = 0; rr < 4; ++rr) {
                const float g = accg[i][j][rr] + bgv;
                const float v = accr[i][j][rr] + brv;
                tmp[rr] = f2bf(0.5f * v / (1.f + __expf(-g)));
            }
            ushort4 pk; pk.x = tmp[0]; pk.y = tmp[1]; pk.z = tmp[2]; pk.w = tmp[3];
            *(ushort4*)(Rel2 + (((size_t)p * B_ + bidx) * H_ + h) * S_ + s0) = pk;
        }
    }
}

// ---------- GEMM 2: self-loop GEMM + adjacency contraction + ReLU ----------
// 28 iterations of the same 2-phase loop: q<12 = loop GEMM (X . Wl^T, K=768),
// q>=12 = adjacency (8p x 2 halves). Same MFMA form both phases. No SBuf.
// grid (12 h-tiles of 64, 16 batches), block 256 (4 waves 2x2).
__global__ __launch_bounds__(256, 2)
void gemm2_kernel(const u16* __restrict__ adjA, const u16* __restrict__ Rel2,
                  const u16* __restrict__ Xc, const u16* __restrict__ Wlb,
                  int layer,
                  u16* __restrict__ Xn, float* __restrict__ Out, int lastLayer) {
    __shared__ __align__(16) char smem2[49152];   // 2 x (A 16K + B 8K)

    const int tid = threadIdx.x;
    const int lane = tid & 63;
    const int w = tid >> 6;
    const int wm = w >> 1, wn = w & 1;
    const int l15 = lane & 15;
    const int hi16 = (lane >> 4) << 4;
    const int h0 = blockIdx.x * 64;
    const int b = blockIdx.y;

    const char* gX  = (const char*)Xc + ((size_t)b * S_) * (H_ * 2);
    const char* gWl = (const char*)(Wlb + (size_t)layer * H_ * H_) + (size_t)h0 * (H_ * 2);

    auto STAGE = [&](int q, int c) {
        char* base = smem2 + c * 24576;
        if (q < 12) {
            stage_tile(gX + (size_t)q * 128, H_ * 2, (u16*)base, tid);
            stage64(gWl + (size_t)q * 128, H_ * 2, base + 16384, tid);
        } else {
            const int qa = q - 12;
            const int p = qa >> 1, sc = qa & 1;
            const char* Ab = (const char*)adjA + ((size_t)p * B_ + b) * (S_ * S_ * 2) + sc * 128;
            const char* Bb = (const char*)Rel2 + (((size_t)p * B_ + b) * H_ + h0) * (S_ * 2) + sc * 128;
            stage_tile(Ab, S_ * 2, (u16*)base, tid);
            stage64(Bb, S_ * 2, base + 16384, tid);
        }
    };

    const f32x4 zf = {0.f, 0.f, 0.f, 0.f};
    f32x4 acc[4][2];
    #pragma unroll
    for (int i = 0; i < 4; ++i)
        #pragma unroll
        for (int j = 0; j < 2; ++j) acc[i][j] = zf;

    STAGE(0, 0);
    __syncthreads();

    for (int q = 0; q < 28; ++q) {
        const int c = q & 1;
        if (q < 27) STAGE(q + 1, c ^ 1);
        const u16* lA = (const u16*)(smem2 + c * 24576);
        const u16* lB = (const u16*)(smem2 + c * 24576 + 16384);
        #pragma unroll
        for (int kq = 0; kq < 2; ++kq) {
            const int ck = kq * 64 + hi16;
            s16x8 a[4], bb[2];
            #pragma unroll
            for (int i = 0; i < 4; ++i)
                a[i] = read_frag(lA, wm * 64 + i * 16 + l15, ck);
            #pragma unroll
            for (int j = 0; j < 2; ++j)
                bb[j] = read_frag(lB, wn * 32 + j * 16 + l15, ck);
            #pragma unroll
            for (int i = 0; i < 4; ++i)
                #pragma unroll
                for (int j = 0; j < 2; ++j)
                    acc[i][j] = mfma16(a[i], bb[j], acc[i][j]);
        }
        __syncthreads();
    }

    #pragma unroll
    for (int i = 0; i < 4; ++i) {
        const int tl = wm * 64 + i * 16 + ((lane >> 4) << 2);
        #pragma unroll
        for (int j = 0; j < 2; ++j) {
            const int h = h0 + wn * 32 + j * 16 + l15;
            #pragma unroll
            for (int rr = 0; rr < 4; ++rr) {
                const size_t t = (size_t)b * S_ + tl + rr;
                float v = fmaxf(acc[i][j][rr], 0.f);
                if (lastLayer) Out[t * H_ + h] = v;
                else           Xn[t * H_ + h] = f2bf(v);
            }
        }
    }
}

// ---------- launch ----------
extern "C" void kernel_launch(void* const* d_in, const int* in_sizes, int n_in,
                              void* d_out, int out_size, void* d_ws, size_t ws_size,
                              hipStream_t stream) {
    const float* sent   = (const float*)d_in[0];
    const float* adj    = (const float*)d_in[1];
    const float* W_in   = (const float*)d_in[2];
    const float* b_in   = (const float*)d_in[3];
    const float* W_out  = (const float*)d_in[4];
    const float* b_out  = (const float*)d_in[5];
    const float* Wg_in  = (const float*)d_in[6];
    const float* bg_in  = (const float*)d_in[7];
    const float* Wg_out = (const float*)d_in[8];
    const float* bg_out = (const float*)d_in[9];
    const float* W_loop = (const float*)d_in[10];

    char* ws = (char*)d_ws;
    u16* Wg_all = (u16*)(ws);                  // 18,874,368 B
    u16* W_all  = (u16*)(ws + 18874368);       // 18,874,368 B
    u16* Wlb    = (u16*)(ws + 37748736);       //  2,359,296 B
    u16* adjA   = (u16*)(ws + 40108032);       //  4,194,304 B
    u16* X0     = (u16*)(ws + 44302336);       //  3,145,728 B
    u16* X1     = (u16*)(ws + 47448064);       //  3,145,728 B
    u16* Rel2   = (u16*)(ws + 50593792);       // 25,165,824 B  (end 75,759,616)

    prep_weights<<<4608, 256, 0, stream>>>(Wg_in, Wg_out, W_in, W_out, W_loop, sent,
                                           Wg_all, W_all, Wlb, X0);
    prep_adj<<<8192, 256, 0, stream>>>(adj, adjA);

    u16* Xc = X0;
    u16* Xn = X1;
    for (int l = 0; l < L_; ++l) {
        gemm1_kernel<<<384, 512, 0, stream>>>(Xc, Wg_all, W_all,
                                              bg_in, bg_out, b_in, b_out,
                                              l, Rel2);
        gemm2_kernel<<<dim3(12, 16), 256, 0, stream>>>(adjA, Rel2, Xc, Wlb, l,
                                                       Xn, (float*)d_out, l == L_ - 1);
        u16* t = Xc; Xc = Xn; Xn = t;
    }
}

// Round 12
// 152.886 us; speedup vs baseline: 1.5870x; 1.0574x over previous
//
#include <hip/hip_runtime.h>
#include <stdint.h>

#define B_ 16
#define S_ 128
#define H_ 768
#define K_ 4
#define L_ 2
#define T_ (B_*S_)   // 2048

typedef __attribute__((ext_vector_type(4))) float f32x4;
typedef __attribute__((ext_vector_type(8))) short s16x8;
typedef __bf16 bf16x8 __attribute__((ext_vector_type(8)));
typedef unsigned short u16;

// ---------- bf16 helpers ----------
__device__ inline u16 f2bf(float f) {
    union { float f; uint32_t u; } v; v.f = f;
    uint32_t u = v.u;
    return (u16)((u + 0x7fffu + ((u >> 16) & 1u)) >> 16);
}

__device__ inline ushort4 f2bf4(float4 v) {
    ushort4 r; r.x = f2bf(v.x); r.y = f2bf(v.y); r.z = f2bf(v.z); r.w = f2bf(v.w);
    return r;
}

// ---------- MFMA wrapper: tolerant to either builtin signature ----------
template <typename T>
__device__ inline auto mfma16_impl(T a, T b, f32x4 c, int)
    -> decltype(__builtin_amdgcn_mfma_f32_16x16x32_bf16(a, b, c, 0, 0, 0)) {
    return __builtin_amdgcn_mfma_f32_16x16x32_bf16(a, b, c, 0, 0, 0);
}
template <typename T>
__device__ inline f32x4 mfma16_impl(T a, T b, f32x4 c, long) {
    return __builtin_amdgcn_mfma_f32_16x16x32_bf16(
        __builtin_bit_cast(bf16x8, a), __builtin_bit_cast(bf16x8, b), c, 0, 0, 0);
}
__device__ inline f32x4 mfma16(s16x8 a, s16x8 b, f32x4 c) {
    return mfma16_impl(a, b, c, 0);
}

// ---------- async global->LDS, 16B/lane ----------
__device__ inline void gload_lds16(const void* g, void* l) {
    __builtin_amdgcn_global_load_lds(
        (__attribute__((address_space(1))) void*)(g),
        (__attribute__((address_space(3))) void*)(l), 16, 0, 0);
}

// ---- 512-thread (8-wave) stage of a 128x64-bf16 tile (XOR-swizzled, proven) ----
__device__ inline void stage128(const char* gRow0, int rowStrideBytes, char* ldsBase, int tid) {
    const int lane = tid & 63;
    const int w = tid >> 6;           // 0..7
    const int lr = lane >> 3;
    #pragma unroll
    for (int j = 0; j < 2; ++j) {
        const int seg = w * 2 + j;          // 0..15
        const int row = seg * 8 + lr;       // 0..127
        const int sb = ((lane & 7) << 4) ^ ((row & 7) << 4);
        gload_lds16(gRow0 + (size_t)row * rowStrideBytes + sb,
                    ldsBase + seg * 1024);
    }
}

// ---- 256-thread (4-wave) stage of a 128x64-bf16 tile (gemm2) ----
__device__ inline void stage_tile(const char* gbase, int rowStrideBytes, u16* lds, int tid) {
    const int lane = tid & 63;
    const int w = tid >> 6;
    const int lr = lane >> 3;
    const int cb = (lane & 7) << 4;
    #pragma unroll
    for (int j = 0; j < 4; ++j) {
        const int seg = j * 4 + w;
        const int row = seg * 8 + lr;
        const int sb = cb ^ ((row & 7) << 4);
        gload_lds16(gbase + (size_t)row * rowStrideBytes + sb, lds + seg * 512);
    }
}

// ---- 256-thread stage of a 64x64-bf16 tile (gemm2) ----
__device__ inline void stage64(const char* gbase, int rowStrideBytes, char* lds, int tid) {
    const int lane = tid & 63;
    const int w = tid >> 6;
    const int lr = lane >> 3;
    const int cb = (lane & 7) << 4;
    #pragma unroll
    for (int j = 0; j < 2; ++j) {
        const int seg = j * 4 + w;
        const int row = seg * 8 + lr;
        const int sb = cb ^ ((row & 7) << 4);
        gload_lds16(gbase + (size_t)row * rowStrideBytes + sb, lds + seg * 1024);
    }
}

// Swizzled ds_read_b128 of an MFMA fragment (128-B rows, any contiguous row count)
__device__ inline s16x8 read_frag(const u16* lds, int row, int colByte) {
    const int bir = colByte ^ ((row & 7) << 4);
    return *(const s16x8*)((const char*)lds + row * 128 + bir);
}

// ---------- prep kernels (proven) ----------
__global__ void prep_weights(const float* __restrict__ Wg_in, const float* __restrict__ Wg_out,
                             const float* __restrict__ W_in,  const float* __restrict__ W_out,
                             const float* __restrict__ W_loop, const float* __restrict__ sent,
                             u16* __restrict__ Wg_all, u16* __restrict__ W_all,
                             u16* __restrict__ Wl, u16* __restrict__ X0) {
    const int i4 = blockIdx.x * blockDim.x + threadIdx.x;   // float4 index
    const int NW4 = L_ * K_ * H_ * H_ / 4;                  // 1,179,648
    const int KHH4 = K_ * H_ * H_ / 4;
    if (i4 < NW4) {
        const int l = i4 / KHH4;
        const int rem = i4 - l * KHH4;
        const int d0 = (l * 2) * KHH4 + rem;
        const int d1 = d0 + KHH4;
        ((ushort4*)Wg_all)[d0] = f2bf4(((const float4*)Wg_in)[i4]);
        ((ushort4*)Wg_all)[d1] = f2bf4(((const float4*)Wg_out)[i4]);
        ((ushort4*)W_all)[d0]  = f2bf4(((const float4*)W_in)[i4]);
        ((ushort4*)W_all)[d1]  = f2bf4(((const float4*)W_out)[i4]);
    }
    if (i4 < L_ * H_ * H_ / 4)  ((ushort4*)Wl)[i4] = f2bf4(((const float4*)W_loop)[i4]);
    if (i4 < T_ * H_ / 4)       ((ushort4*)X0)[i4] = f2bf4(((const float4*)sent)[i4]);
}

// adjA[p][b][t][s]: p=dir*4+k; dir 0 (in): adj[b,k,s,t] (transposed), dir 1 (out): adj[b,k,t,s]
__global__ void prep_adj(const float* __restrict__ adj, u16* __restrict__ adjA) {
    const int idx = blockIdx.x * blockDim.x + threadIdx.x;
    const int s = idx & 127;
    const int t = (idx >> 7) & 127;
    const int b = (idx >> 14) & 15;
    const int p = idx >> 18;
    const int dir = p >> 2, k = p & 3;
    const float v = dir ? adj[(((size_t)b * K_ + k) * S_ + t) * S_ + s]
                        : adj[(((size_t)b * K_ + k) * S_ + s) * S_ + t];
    adjA[idx] = f2bf(v);
}

// ---------- GEMM 1: persistent, perfectly balanced (256 blocks x 3 tasks) ----------
// Task = 128tok x 128h (rel+gate), BK=64, 12 K-tiles. Block = 512 threads, 8 waves
// (2m x 4n), per-wave 64tok x 32h rel+gate (acc 64 VGPR). LDS 2 x 48KB dbuf.
// p = bid&7 -> problem pinned to XCD (weights L2-resident); 3 tasks run back-to-back
// in ONE continuous 2-phase pipeline (36 virtual K-tiles, one prologue, zero tail).
// Epilogues are wave-local register dumps at task boundaries (no extra barriers).
__global__ __launch_bounds__(512, 2)
void gemm1_kernel(const u16* __restrict__ Xb,
                  const u16* __restrict__ Wg_all, const u16* __restrict__ W_all,
                  const float* __restrict__ bg_in, const float* __restrict__ bg_out,
                  const float* __restrict__ b_in,  const float* __restrict__ b_out,
                  int layer, u16* __restrict__ Rel2) {
    __shared__ __align__(16) char smem[98304];   // 2 x (A 16K + Br 16K + Bg 16K)

    const int tid = threadIdx.x;
    const int lane = tid & 63;
    const int w = tid >> 6;
    const int wm = w >> 2;                 // 0..1 (64-tok half)
    const int wn = w & 3;                  // 0..3 (32-h slice)
    const int l15 = lane & 15;
    const int hi16 = (lane >> 4) << 4;

    const int bid = blockIdx.x;
    const int p = bid & 7;                 // problem == XCD
    const int g = bid >> 3;                // 0..31 within problem
    const int dir = p >> 2, kk = p & 3;
    const size_t woff = ((size_t)(layer * 2 + dir) * K_ + kk) * (size_t)(H_ * H_);

    // 3 tasks: idx = g*3+i -> y = idx/16 (h-tile), m = idx%16 (batch)
    const char* gAt[3];
    const char* gBrt[3];
    const char* gBgt[3];
    int ys[3], ms[3];
    #pragma unroll
    for (int i = 0; i < 3; ++i) {
        const int task = g * 3 + i;
        const int y = task / 16, m = task % 16;
        ys[i] = y; ms[i] = m;
        gAt[i]  = (const char*)Xb + (size_t)(m * 128) * (H_ * 2);
        gBrt[i] = (const char*)(W_all + woff)  + (size_t)(y * 128) * (H_ * 2);
        gBgt[i] = (const char*)(Wg_all + woff) + (size_t)(y * 128) * (H_ * 2);
    }

    const float* bgp = (dir ? bg_out : bg_in) + ((size_t)layer * K_ + kk) * H_;
    const float* brp = (dir ? b_out  : b_in ) + ((size_t)layer * K_ + kk) * H_;

    auto STAGE = [&](int i, int kt, int c) {
        char* base = smem + c * 49152;
        stage128(gAt[i]  + (size_t)kt * 128, H_ * 2, base, tid);
        stage128(gBrt[i] + (size_t)kt * 128, H_ * 2, base + 16384, tid);
        stage128(gBgt[i] + (size_t)kt * 128, H_ * 2, base + 32768, tid);
    };

    const f32x4 zf = {0.f, 0.f, 0.f, 0.f};
    f32x4 accr[4][2], accg[4][2];
    #pragma unroll
    for (int i = 0; i < 4; ++i)
        #pragma unroll
        for (int j = 0; j < 2; ++j) { accr[i][j] = zf; accg[i][j] = zf; }

    STAGE(0, 0, 0);
    __syncthreads();

    #pragma unroll
    for (int ti = 0; ti < 3; ++ti) {
        for (int kt = 0; kt < 12; ++kt) {
            const int c = kt & 1;
            if (kt < 11)      STAGE(ti, kt + 1, c ^ 1);
            else if (ti < 2)  STAGE(ti + 1, 0, c ^ 1);
            const u16* lA  = (const u16*)(smem + c * 49152);
            const u16* lBr = (const u16*)(smem + c * 49152 + 16384);
            const u16* lBg = (const u16*)(smem + c * 49152 + 32768);
            #pragma unroll
            for (int kq = 0; kq < 2; ++kq) {
                const int ck = kq * 64 + hi16;
                s16x8 a[4], br[2], bg[2];
                #pragma unroll
                for (int i = 0; i < 4; ++i)
                    a[i] = read_frag(lA, wm * 64 + i * 16 + l15, ck);
                #pragma unroll
                for (int j = 0; j < 2; ++j) {
                    br[j] = read_frag(lBr, wn * 32 + j * 16 + l15, ck);
                    bg[j] = read_frag(lBg, wn * 32 + j * 16 + l15, ck);
                }
                #pragma unroll
                for (int i = 0; i < 4; ++i) {
                    #pragma unroll
                    for (int j = 0; j < 2; ++j) {
                        accr[i][j] = mfma16(a[i], br[j], accr[i][j]);
                        accg[i][j] = mfma16(a[i], bg[j], accg[i][j]);
                    }
                }
            }
            __syncthreads();
        }
        // ---- wave-local epilogue for task ti (no barrier; next task's tile 0
        // is already staged and drained by the kt=11 __syncthreads) ----
        {
            const int y = ys[ti], m = ms[ti];
            #pragma unroll
            for (int j = 0; j < 2; ++j) {
                const int h = y * 128 + wn * 32 + j * 16 + l15;
                const float bgv = bgp[h];
                const float brv = brp[h];
                #pragma unroll
                for (int i = 0; i < 4; ++i) {
                    const int tl = wm * 64 + i * 16 + ((lane >> 4) << 2);   // 0..127
                    u16 tmp[4];
                    #pragma unroll
                    for (int rr = 0; rr < 4; ++rr) {
                        const float gv = accg[i][j][rr] + bgv;
                        const float vv = accr[i][j][rr] + brv;
                        tmp[rr] = f2bf(0.5f * vv / (1.f + __expf(-gv)));
                    }
                    ushort4 pk; pk.x = tmp[0]; pk.y = tmp[1]; pk.z = tmp[2]; pk.w = tmp[3];
                    *(ushort4*)(Rel2 + (((size_t)p * B_ + m) * H_ + h) * S_ + tl) = pk;
                    accr[i][j] = zf; accg[i][j] = zf;
                }
            }
        }
    }
}

// ---------- GEMM 2: self-loop GEMM + adjacency contraction + ReLU (r11, proven) ----------
// 28 iterations: q<12 = loop GEMM (X . Wl^T, K=768), q>=12 = adjacency (8p x 2).
// grid (12 h-tiles of 64, 16 batches), block 256 (4 waves 2x2).
__global__ __launch_bounds__(256, 2)
void gemm2_kernel(const u16* __restrict__ adjA, const u16* __restrict__ Rel2,
                  const u16* __restrict__ Xc, const u16* __restrict__ Wlb,
                  int layer,
                  u16* __restrict__ Xn, float* __restrict__ Out, int lastLayer) {
    __shared__ __align__(16) char smem2[49152];   // 2 x (A 16K + B 8K)

    const int tid = threadIdx.x;
    const int lane = tid & 63;
    const int w = tid >> 6;
    const int wm = w >> 1, wn = w & 1;
    const int l15 = lane & 15;
    const int hi16 = (lane >> 4) << 4;
    const int h0 = blockIdx.x * 64;
    const int b = blockIdx.y;

    const char* gX  = (const char*)Xc + ((size_t)b * S_) * (H_ * 2);
    const char* gWl = (const char*)(Wlb + (size_t)layer * H_ * H_) + (size_t)h0 * (H_ * 2);

    auto STAGE = [&](int q, int c) {
        char* base = smem2 + c * 24576;
        if (q < 12) {
            stage_tile(gX + (size_t)q * 128, H_ * 2, (u16*)base, tid);
            stage64(gWl + (size_t)q * 128, H_ * 2, base + 16384, tid);
        } else {
            const int qa = q - 12;
            const int p = qa >> 1, sc = qa & 1;
            const char* Ab = (const char*)adjA + ((size_t)p * B_ + b) * (S_ * S_ * 2) + sc * 128;
            const char* Bb = (const char*)Rel2 + (((size_t)p * B_ + b) * H_ + h0) * (S_ * 2) + sc * 128;
            stage_tile(Ab, S_ * 2, (u16*)base, tid);
            stage64(Bb, S_ * 2, base + 16384, tid);
        }
    };

    const f32x4 zf = {0.f, 0.f, 0.f, 0.f};
    f32x4 acc[4][2];
    #pragma unroll
    for (int i = 0; i < 4; ++i)
        #pragma unroll
        for (int j = 0; j < 2; ++j) acc[i][j] = zf;

    STAGE(0, 0);
    __syncthreads();

    for (int q = 0; q < 28; ++q) {
        const int c = q & 1;
        if (q < 27) STAGE(q + 1, c ^ 1);
        const u16* lA = (const u16*)(smem2 + c * 24576);
        const u16* lB = (const u16*)(smem2 + c * 24576 + 16384);
        #pragma unroll
        for (int kq = 0; kq < 2; ++kq) {
            const int ck = kq * 64 + hi16;
            s16x8 a[4], bb[2];
            #pragma unroll
            for (int i = 0; i < 4; ++i)
                a[i] = read_frag(lA, wm * 64 + i * 16 + l15, ck);
            #pragma unroll
            for (int j = 0; j < 2; ++j)
                bb[j] = read_frag(lB, wn * 32 + j * 16 + l15, ck);
            #pragma unroll
            for (int i = 0; i < 4; ++i)
                #pragma unroll
                for (int j = 0; j < 2; ++j)
                    acc[i][j] = mfma16(a[i], bb[j], acc[i][j]);
        }
        __syncthreads();
    }

    #pragma unroll
    for (int i = 0; i < 4; ++i) {
        const int tl = wm * 64 + i * 16 + ((lane >> 4) << 2);
        #pragma unroll
        for (int j = 0; j < 2; ++j) {
            const int h = h0 + wn * 32 + j * 16 + l15;
            #pragma unroll
            for (int rr = 0; rr < 4; ++rr) {
                const size_t t = (size_t)b * S_ + tl + rr;
                float v = fmaxf(acc[i][j][rr], 0.f);
                if (lastLayer) Out[t * H_ + h] = v;
                else           Xn[t * H_ + h] = f2bf(v);
            }
        }
    }
}

// ---------- launch ----------
extern "C" void kernel_launch(void* const* d_in, const int* in_sizes, int n_in,
                              void* d_out, int out_size, void* d_ws, size_t ws_size,
                              hipStream_t stream) {
    const float* sent   = (const float*)d_in[0];
    const float* adj    = (const float*)d_in[1];
    const float* W_in   = (const float*)d_in[2];
    const float* b_in   = (const float*)d_in[3];
    const float* W_out  = (const float*)d_in[4];
    const float* b_out  = (const float*)d_in[5];
    const float* Wg_in  = (const float*)d_in[6];
    const float* bg_in  = (const float*)d_in[7];
    const float* Wg_out = (const float*)d_in[8];
    const float* bg_out = (const float*)d_in[9];
    const float* W_loop = (const float*)d_in[10];

    char* ws = (char*)d_ws;
    u16* Wg_all = (u16*)(ws);                  // 18,874,368 B
    u16* W_all  = (u16*)(ws + 18874368);       // 18,874,368 B
    u16* Wlb    = (u16*)(ws + 37748736);       //  2,359,296 B
    u16* adjA   = (u16*)(ws + 40108032);       //  4,194,304 B
    u16* X0     = (u16*)(ws + 44302336);       //  3,145,728 B
    u16* X1     = (u16*)(ws + 47448064);       //  3,145,728 B
    u16* Rel2   = (u16*)(ws + 50593792);       // 25,165,824 B  (end 75,759,616)

    prep_weights<<<4608, 256, 0, stream>>>(Wg_in, Wg_out, W_in, W_out, W_loop, sent,
                                           Wg_all, W_all, Wlb, X0);
    prep_adj<<<8192, 256, 0, stream>>>(adj, adjA);

    u16* Xc = X0;
    u16* Xn = X1;
    for (int l = 0; l < L_; ++l) {
        gemm1_kernel<<<256, 512, 0, stream>>>(Xc, Wg_all, W_all,
                                              bg_in, bg_out, b_in, b_out,
                                              l, Rel2);
        gemm2_kernel<<<dim3(12, 16), 256, 0, stream>>>(adjA, Rel2, Xc, Wlb, l,
                                                       Xn, (float*)d_out, l == L_ - 1);
        u16* t = Xc; Xc = Xn; Xn = t;
    }
}